// Round 11
// baseline (77.371 us; speedup 1.0000x reference)
//
#include <hip/hip_runtime.h>

#define BB 16
#define SS 2048
#define DD 64
#define OO 128
#define SPL 16
#define YEL (OO * DD)   // 8192 elems per Y[b] (and per slab)

typedef __attribute__((ext_vector_type(8))) short short8;   // 8 bf16 = 4 VGPRs
typedef __attribute__((ext_vector_type(4))) float f32x4;

__device__ __forceinline__ unsigned short f2bf(float f) {   // RNE fp32->bf16
    unsigned int u = __float_as_uint(f);
    return (unsigned short)((u + 0x7FFF + ((u >> 16) & 1)) >> 16);
}
__device__ __forceinline__ unsigned int pk2(float x, float y) {
    return (unsigned int)f2bf(x) | ((unsigned int)f2bf(y) << 16);
}
__device__ __forceinline__ short8 cvt8(float4 a, float4 b) {
    uint4 u = make_uint4(pk2(a.x, a.y), pk2(a.z, a.w), pk2(b.x, b.y), pk2(b.z, b.w));
    return *(short8*)&u;
}
__device__ __forceinline__ float bflo(unsigned int u) { return __uint_as_float(u << 16); }
__device__ __forceinline__ float bfhi(unsigned int u) { return __uint_as_float(u & 0xffff0000u); }

// swizzled element index within a Y[b] / slab: o in [0,128), d in [0,64)
__device__ __forceinline__ int yswz(int o, int d) {
    return (o << 6) + ((((d >> 3) ^ (o & 7)) << 3) | (d & 7));
}

// ---------------------------------------------------------------------------
// D1 k_yf (R9-verified body): slab[b][p] = partial Y over 128-t slice, bf16,
// XOR-swizzled. Epilogue (R10): D-frags -> reused XT LDS -> 2 coalesced
// global_store_dwordx4/thread instead of 16 scattered 2B stores.
// grid 256 = (b = bx&15, p = bx>>4), 512 thr (8 waves).
// ---------------------------------------------------------------------------
__global__ __launch_bounds__(512) void k_yf(const float* __restrict__ X,
                                            const float* __restrict__ W,
                                            unsigned short* __restrict__ YpB) {
    __shared__ __align__(16) unsigned short XT[64 * 132];   // staging, then slab exchange

    const int bx  = blockIdx.x;
    const int b   = bx & 15;
    const int p   = bx >> 4;
    const int t0  = p * (SS / SPL);
    const int tid = threadIdx.x;
    const int w   = tid >> 6;     // 0..7
    const int l   = tid & 63;

    const float* Xb = X + ((size_t)b * SS + t0) * DD;
#pragma unroll
    for (int i = 0; i < 4; ++i) {
        const int tl = w * 4 + i * 32;
        const float x0 = Xb[(size_t)(tl + 0) * DD + l];
        const float x1 = Xb[(size_t)(tl + 1) * DD + l];
        const float x2 = Xb[(size_t)(tl + 2) * DD + l];
        const float x3 = Xb[(size_t)(tl + 3) * DD + l];
        *(uint2*)&XT[l * 132 + tl] = make_uint2(pk2(x0, x1), pk2(x2, x3));
    }
    __syncthreads();

    const int n = l & 15;
    const int q = l >> 4;

    f32x4 acc[4];
#pragma unroll
    for (int j = 0; j < 4; ++j) acc[j] = {0.f, 0.f, 0.f, 0.f};

    const float* Wr = W + (size_t)(w * 16 + n) * SS + t0;
#pragma unroll
    for (int kk = 0; kk < SS / SPL; kk += 32) {
        const float4 wa = *(const float4*)(Wr + kk + q * 8);
        const float4 wb = *(const float4*)(Wr + kk + q * 8 + 4);
        const short8 a  = cvt8(wa, wb);
#pragma unroll
        for (int j = 0; j < 4; ++j) {
            const unsigned short* r = &XT[(j * 16 + n) * 132 + kk + q * 8];
            const uint2 lo = *(const uint2*)(r);
            const uint2 hi = *(const uint2*)(r + 4);
            uint4 u = make_uint4(lo.x, lo.y, hi.x, hi.y);
            acc[j] = __builtin_amdgcn_mfma_f32_16x16x32_bf16(a, *(short8*)&u, acc[j], 0, 0, 0);
        }
    }

    // ---- epilogue: exchange through XT (reuse), then coalesced stores ----
    __syncthreads();                        // all XT staging reads complete
#pragma unroll
    for (int j = 0; j < 4; ++j)
#pragma unroll
        for (int r = 0; r < 4; ++r)
            XT[yswz(w * 16 + q * 4 + r, j * 16 + n)] = f2bf(acc[j][r]);
    __syncthreads();

    uint4* slab4 = (uint4*)(YpB + (size_t)(b * SPL + p) * YEL);   // 1024 chunks
    const uint4* xt4 = (const uint4*)XT;
#pragma unroll
    for (int i = 0; i < 2; ++i)
        slab4[tid + 512 * i] = xt4[tid + 512 * i];
}

// ---------------------------------------------------------------------------
// D2 k_out2 (R9-verified reduce + MFMA): inline reduction of 16 bf16 slabs ->
// YL (swizzled LDS), out-tile MFMA with B-frags from YL.
// Epilogue: two-pass half-width WAVE-PRIVATE exchange, Ow[8][16*68]
// (8 waves! — R10's Ow[4] OOB was the NaN). Per pass: write 16 vals+bias
// (2-way banks = free), 4 ds_read_b128 + 4 global_store_dwordx4 with 256B
// contiguous runs. No extra barriers (same-wave LDS ordering).
// grid 256 = (b = bx&15, st = bx>>4), 512 thr (8 waves).
// ---------------------------------------------------------------------------
__global__ __launch_bounds__(512) void k_out2(const float* __restrict__ X,
                                              const unsigned short* __restrict__ YpB,
                                              const float* __restrict__ bias,
                                              float* __restrict__ out) {
    __shared__ __align__(16) unsigned short YL[YEL];   // 16KB swizzled bf16 Y[b]
    __shared__ __align__(16) float Ow[8][16 * 68];     // 34.8KB per-wave exchange

    const int bx  = blockIdx.x;
    const int b   = bx & 15;
    const int st  = bx >> 4;
    const int tid = threadIdx.x;
    const int w   = tid >> 6;     // 0..7
    const int l   = tid & 63;
    const int n   = l & 15;
    const int q   = l >> 4;

    // ---- stage: reduce 16 slabs elementwise (coalesced uint4 chunks) ----
    const uint4* Yb4 = (const uint4*)(YpB + (size_t)b * SPL * YEL);
#pragma unroll
    for (int c = tid; c < YEL / 8; c += 512) {   // 2 chunks/thread
        float s[8];
#pragma unroll
        for (int e = 0; e < 8; ++e) s[e] = 0.f;
#pragma unroll
        for (int pp = 0; pp < SPL; ++pp) {
            const uint4 v = Yb4[(size_t)pp * (YEL / 8) + c];
            s[0] += bflo(v.x); s[1] += bfhi(v.x);
            s[2] += bflo(v.y); s[3] += bfhi(v.y);
            s[4] += bflo(v.z); s[5] += bfhi(v.z);
            s[6] += bflo(v.w); s[7] += bfhi(v.w);
        }
        ((uint4*)YL)[c] = make_uint4(pk2(s[0], s[1]), pk2(s[2], s[3]),
                                     pk2(s[4], s[5]), pk2(s[6], s[7]));
    }

    const int s0 = st * 128;
    float bv[8];
#pragma unroll
    for (int j = 0; j < 8; ++j) bv[j] = bias[j * 16 + n];

    f32x4 acc[8];
#pragma unroll
    for (int j = 0; j < 8; ++j) acc[j] = {0.f, 0.f, 0.f, 0.f};

    __syncthreads();

    // ---- MFMA: out tile (R9-verified math, B-frags from LDS) ----
    const float* Xr = X + ((size_t)b * SS + s0 + w * 16 + n) * DD;
#pragma unroll
    for (int kk = 0; kk < DD; kk += 32) {
        const float4 xa = *(const float4*)(Xr + kk + q * 8);
        const float4 xb = *(const float4*)(Xr + kk + q * 8 + 4);
        const short8 a  = cvt8(xa, xb);
        const int c8    = (kk >> 3) + q;
#pragma unroll
        for (int j = 0; j < 8; ++j) {
            const int o = j * 16 + n;
            const uint4 u = *(const uint4*)&YL[(o << 6) + (((c8 ^ (o & 7)) << 3))];
            acc[j] = __builtin_amdgcn_mfma_f32_16x16x32_bf16(a, *(short8*)&u, acc[j], 0, 0, 0);
        }
    }

    // ---- epilogue: two-pass half-width wave-private exchange ----
    float* ow = Ow[w];
    float* ob = out + ((size_t)b * SS + s0 + w * 16) * OO;
    const int hr  = l >> 4;      // read row group 0..3
    const int c16 = l & 15;      // 16B chunk within 64-col half-row
#pragma unroll
    for (int pass = 0; pass < 2; ++pass) {
        // write this half's 4x4 acc values (+bias); 2-way banks = free
#pragma unroll
        for (int j = 0; j < 4; ++j) {
            const int jj = pass * 4 + j;
#pragma unroll
            for (int r = 0; r < 4; ++r)
                ow[(q * 4 + r) * 68 + j * 16 + n] = acc[jj][r] + bv[jj];
        }
        // same-wave LDS RAW: in-order DS ops + compiler lgkmcnt; no barrier
#pragma unroll
        for (int it = 0; it < 4; ++it) {
            const int row = hr + it * 4;
            const float4 v = *(const float4*)&ow[row * 68 + c16 * 4];
            *(float4*)(ob + (size_t)row * OO + pass * 64 + c16 * 4) = v;
        }
    }
}

extern "C" void kernel_launch(void* const* d_in, const int* in_sizes, int n_in,
                              void* d_out, int out_size, void* d_ws, size_t ws_size,
                              hipStream_t stream) {
    const float* X    = (const float*)d_in[0];  // [B,S,D]
    const float* W    = (const float*)d_in[1];  // [OUT,S]
    const float* bias = (const float*)d_in[2];  // [OUT]
    float* out = (float*)d_out;                 // [B,S,OUT]

    unsigned short* YpB = (unsigned short*)d_ws;   // [B*SPL][YEL] bf16 slabs, 4.2MB

    k_yf <<<dim3(256), dim3(512), 0, stream>>>(X, W, YpB);
    k_out2<<<dim3(256), dim3(512), 0, stream>>>(X, YpB, bias, out);
}